// Round 6
// baseline (3689.582 us; speedup 1.0000x reference)
//
#include <hip/hip_runtime.h>
#include <hip/hip_fp16.h>

#define T_SZ 365
#define IN_SZ 32
#define H_SZ 256
#define G4 1024
#define K_SZ 288
#define KP 296        // padded LDS row stride (halfs); 592 B = 16B-aligned rows
#define M_GRP 32      // batch rows per 2-block group
#define N_GRP 128     // groups (128*32 = 4096)
#define NTHR 512      // 8 waves; wave w owns 16 j-cols x 4 gates
#define NBLK 256      // 1 block per CU, all co-resident

// workspace offsets (bytes)
#define FLG_OFF (640*1024)
#define HX_OFF  (1024*1024)

typedef _Float16 f16x8 __attribute__((ext_vector_type(8)));
typedef float f32x4 __attribute__((ext_vector_type(4)));
typedef unsigned long long u64;

__device__ __forceinline__ float fast_sigmoid(float x) {
    float e = __builtin_amdgcn_exp2f(-1.4426950408889634f * x);
    return __builtin_amdgcn_rcpf(1.0f + e);
}
__device__ __forceinline__ float fast_tanh(float x) {
    float e = __builtin_amdgcn_exp2f(2.8853900817779268f * x);
    return 1.0f - 2.0f * __builtin_amdgcn_rcpf(1.0f + e);
}

// Pack W = [w_hh | w_ih] as fp16, layout [gate-row][k] (k contiguous) = B^T.
__global__ void pack_w_kernel(const float* __restrict__ w_ih,
                              const float* __restrict__ w_hh,
                              _Float16* __restrict__ wp) {
    int idx = blockIdx.x * 256 + threadIdx.x;
    if (idx >= G4 * K_SZ) return;
    int g = idx / K_SZ, k = idx - g * K_SZ;
    float v = (k < H_SZ) ? w_hh[g * H_SZ + k] : w_ih[g * IN_SZ + (k - H_SZ)];
    wp[idx] = (_Float16)v;
}

__global__ void init_sync_kernel(unsigned int* flags) {
    int i = blockIdx.x * 256 + threadIdx.x;
    if (i < 2 * N_GRP) flags[i * 16] = 0u;   // one flag per 64 B
}

__global__ __launch_bounds__(NTHR, 2) void lstm_kernel(
    const float* __restrict__ xd, const float* __restrict__ b,
    const _Float16* __restrict__ wp, const float* __restrict__ w_out,
    const float* __restrict__ b_out, float* __restrict__ out,
    u64* hx, unsigned int* flags)
{
    // A-operand: h (cols 0..255, global j) + x (cols 256..287)
    __shared__ _Float16 a_s[M_GRP * KP];   // 18,944 B

    const int tid  = threadIdx.x;
    const int wave = tid >> 6;       // 0..7: owns j-cols [q*128 + wave*16, +16), all 4 gates
    const int lane = tid & 63;
    const int quad = lane >> 4;
    const int l16  = lane & 15;
    const int blk  = blockIdx.x;
    const int q    = blk >> 7;       // pair member 0/1: owns j in [q*128, +128)
    const int g    = blk & 127;      // group id (batch rows [g*32, +32))

    // ---- W slice (4 gates x 16 j-cols x K=288) into registers: 144 regs/lane ----
    f16x8 wfr[4][9];
#pragma unroll
    for (int G = 0; G < 4; ++G) {
        const _Float16* wr = wp + (size_t)(G * 256 + q * 128 + wave * 16 + l16) * K_SZ + quad * 8;
#pragma unroll
        for (int kt = 0; kt < 9; ++kt)
            wfr[G][kt] = *(const f16x8*)(wr + kt * 32);
    }

    float bias[4];
#pragma unroll
    for (int G = 0; G < 4; ++G) bias[G] = b[G * 256 + q * 128 + wave * 16 + l16];

    for (int i = tid; i < M_GRP * KP; i += NTHR) a_s[i] = (_Float16)0.f;

    // x loader: 32 rows x 32 floats = 1024 floats; thread owns 2 consecutive of one row
    const int mx = tid >> 4;           // row 0..31
    const int e0 = (tid & 15) * 2;     // element 0..30
    const float* xrow = xd + (size_t)(g * M_GRP + mx) * (T_SZ * IN_SZ) + e0;
    float2 xv = *(const float2*)xrow;  // t = 0

    f32x4 creg[2];
    creg[0] = (f32x4){0.f, 0.f, 0.f, 0.f};
    creg[1] = (f32x4){0.f, 0.f, 0.f, 0.f};

    // stage x_0
    a_s[mx * KP + H_SZ + e0]     = (_Float16)xv.x;
    a_s[mx * KP + H_SZ + e0 + 1] = (_Float16)xv.y;
    __syncthreads();

    const _Float16* arow0 = &a_s[l16 * KP + quad * 8];
    const _Float16* arow1 = arow0 + 16 * KP;
    const int jcol = q * 128 + wave * 16 + l16;   // this lane's global h column

    unsigned int* myflag = &flags[(g * 2 + q) * 16];
    unsigned int* pflag  = &flags[(g * 2 + (q ^ 1)) * 16];
    const f32x4 vzero = {0.f, 0.f, 0.f, 0.f};

    for (int t = 0; t < T_SZ; ++t) {
        // ---- GEMM: preacts[32 x 512-slice] = A[32 x 288] @ Wslice^T (W in regs) ----
        f32x4 acc[2][4];
#pragma unroll
        for (int mt = 0; mt < 2; ++mt)
#pragma unroll
            for (int G = 0; G < 4; ++G) acc[mt][G] = vzero;

#pragma unroll
        for (int kt = 0; kt < 9; ++kt) {
            f16x8 a0 = *(const f16x8*)(arow0 + kt * 32);
            f16x8 a1 = *(const f16x8*)(arow1 + kt * 32);
#pragma unroll
            for (int G = 0; G < 4; ++G) {
                acc[0][G] = __builtin_amdgcn_mfma_f32_16x16x32_f16(a0, wfr[G][kt], acc[0][G], 0, 0, 0);
                acc[1][G] = __builtin_amdgcn_mfma_f32_16x16x32_f16(a1, wfr[G][kt], acc[1][G], 0, 0, 0);
            }
        }

        // prefetch next x
        if (t + 1 < T_SZ) xv = *(const float2*)(xrow + (size_t)(t + 1) * IN_SZ);

        // ---- activations + state update; h -> own a_s columns ----
#pragma unroll
        for (int mt = 0; mt < 2; ++mt) {
#pragma unroll
            for (int r = 0; r < 4; ++r) {
                float iv = fast_sigmoid(acc[mt][0][r] + bias[0]);
                float fv = fast_sigmoid(acc[mt][1][r] + bias[1]);
                float gv = fast_tanh  (acc[mt][2][r] + bias[2]);
                float ov = fast_sigmoid(acc[mt][3][r] + bias[3]);
                float cv = fv * creg[mt][r] + iv * gv;
                creg[mt][r] = cv;
                float hv = ov * fast_tanh(cv);
                int m = mt * 16 + quad * 4 + r;
                a_s[m * KP + jcol] = (_Float16)hv;
            }
        }
        __syncthreads();

        // ---- push own 8 KB half: [m 0..31][32 u64], 2 u64 per thread ----
        u64* dst = hx + (((size_t)(t & 1) * N_GRP + g) * 2048) + q * 1024;
#pragma unroll
        for (int i = 0; i < 2; ++i) {
            int u = tid + i * 512;          // m = u>>5, c = u&31
            int m = u >> 5, c = u & 31;
            u64 v = *(const u64*)&a_s[m * KP + q * 128 + c * 4];
            __hip_atomic_store(&dst[u], v, __ATOMIC_RELAXED, __HIP_MEMORY_SCOPE_AGENT);
        }
        asm volatile("s_waitcnt vmcnt(0)" ::: "memory");
        __syncthreads();   // all pushes globally visible (acked agent-scope stores)

        // ---- pairwise flag barrier ----
        if (tid == 0) {
            __hip_atomic_store(myflag, (unsigned int)(t + 1),
                               __ATOMIC_RELEASE, __HIP_MEMORY_SCOPE_AGENT);
            while (__hip_atomic_load(pflag, __ATOMIC_ACQUIRE, __HIP_MEMORY_SCOPE_AGENT)
                   < (unsigned int)(t + 1))
                __builtin_amdgcn_s_sleep(1);
        }
        __syncthreads();

        // ---- pull partner 8 KB half ----
        const u64* src = hx + (((size_t)(t & 1) * N_GRP + g) * 2048) + (q ^ 1) * 1024;
        u64 v0 = __hip_atomic_load(&src[tid],       __ATOMIC_RELAXED, __HIP_MEMORY_SCOPE_AGENT);
        u64 v1 = __hip_atomic_load(&src[tid + 512], __ATOMIC_RELAXED, __HIP_MEMORY_SCOPE_AGENT);
        {
            int m0 = tid >> 5,         c0 = tid & 31;
            int m1 = (tid + 512) >> 5, c1 = tid & 31;
            *(u64*)&a_s[m0 * KP + (q ^ 1) * 128 + c0 * 4] = v0;
            *(u64*)&a_s[m1 * KP + (q ^ 1) * 128 + c1 * 4] = v1;
        }
        // stage x_{t+1}
        if (t + 1 < T_SZ) {
            a_s[mx * KP + H_SZ + e0]     = (_Float16)xv.x;
            a_s[mx * KP + H_SZ + e0 + 1] = (_Float16)xv.y;
        }
        __syncthreads();
    }

    // ---- epilogue: out[m] = relu(h_T . w_out + b_out); member q==0 writes ----
    if (q == 0) {
        const int m = tid >> 4, p = tid & 15;
        float s = 0.f;
#pragma unroll
        for (int jj = 0; jj < 16; ++jj) {
            int j = p * 16 + jj;
            s += (float)a_s[m * KP + j] * w_out[j];
        }
        s += __shfl_xor(s, 1);
        s += __shfl_xor(s, 2);
        s += __shfl_xor(s, 4);
        s += __shfl_xor(s, 8);
        if (p == 0) out[(size_t)g * M_GRP + m] = fmaxf(s + b_out[0], 0.f);
    }
}

extern "C" void kernel_launch(void* const* d_in, const int* in_sizes, int n_in,
                              void* d_out, int out_size, void* d_ws, size_t ws_size,
                              hipStream_t stream) {
    const float* xd    = (const float*)d_in[0];
    const float* w_ih  = (const float*)d_in[1];
    const float* w_hh  = (const float*)d_in[2];
    const float* b     = (const float*)d_in[3];
    const float* w_out = (const float*)d_in[4];
    const float* b_out = (const float*)d_in[5];
    float* out = (float*)d_out;

    _Float16* wp = (_Float16*)d_ws;                                // 576 KB @ 0
    unsigned int* flags = (unsigned int*)((char*)d_ws + FLG_OFF);  // 16 KB
    u64* hx = (u64*)((char*)d_ws + HX_OFF);                        // 4 MB (double-buffered)

    pack_w_kernel<<<(G4 * K_SZ + 255) / 256, 256, 0, stream>>>(w_ih, w_hh, wp);
    init_sync_kernel<<<1, 256, 0, stream>>>(flags);
    lstm_kernel<<<NBLK, NTHR, 0, stream>>>(xd, b, wp, w_out, b_out, out, hx, flags);
}